// Round 1
// baseline (169.709 us; speedup 1.0000x reference)
//
#include <hip/hip_runtime.h>
#include <math.h>

// Problem constants (GroupedKANLayer): B=2, C=31, D=7, H=W=192
#define NBATCH 2
#define NC 31
#define ND 7
#define NH 192
#define NW 192
#define HW (NH * NW)            // 36864
#define NP (NBATCH * HW)        // 73728 pixels
#define NBASIS 8
#define CLEN 56                 // ND * NBASIS
#define KP 70                   // CLEN + ND + ND
#define OCB 5                   // 70 = 14 * 5 -> 45 weight SGPRs/ic

// conv tiling (R7): 32x32 tile, wave-private 8-row strips, zero barriers,
// register-pipelined staging. Each thread: 4 pixel rows x 5 oc ->
// 180 FMA / 18 ds_reads per ic (was 90/12).
#define CTSX 32
#define CTSY 32
#define WROWS 8                 // tile rows per wave
#define HROWS 10                // halo rows per wave (8 + 2)
#define HCOLS 34                // halo cols
#define WCELLS (HROWS * HCOLS)  // 340 words per wave
#define NSLOT 6                 // ceil(340/64) staging slots per lane

// kan v9 tiling: 128 px per block, px-pair per lane, 2-way channel split
#define KPX 128

// ---------------------------------------------------------------------------
// Kernel 1: ctx = mean_d x, float4-vectorized (16 B/lane).
// ---------------------------------------------------------------------------
__global__ __launch_bounds__(256) void ctx_mean_kernel(
    const float4* __restrict__ x4, float4* __restrict__ ctx4)
{
    const int HW4 = HW / 4;
    int idx = blockIdx.x * 256 + threadIdx.x;      // over NBATCH*NC*HW4
    if (idx >= NBATCH * NC * HW4) return;
    int hw4 = idx % HW4;
    int bc  = idx / HW4;
    const float4* src = x4 + (size_t)bc * (ND * HW4) + hw4;
    float4 a = src[0];
#pragma unroll
    for (int d = 1; d < ND; ++d) {
        float4 v = src[d * HW4];
        a.x += v.x; a.y += v.y; a.z += v.z; a.w += v.w;
    }
    const float inv = 1.0f / 7.0f;
    a.x *= inv; a.y *= inv; a.z *= inv; a.w *= inv;
    ctx4[idx] = a;
}

// ---------------------------------------------------------------------------
// Kernel 2 (R7): 32x32 tile, 5 oc per block (blockIdx.z -> s_loads).
// Wave-private 10x34 halo strips in LDS, zero barriers, register-pipelined
// staging. Each thread: 4 pixel rows x 5 oc -> 180 FMA / 18 ds_reads per ic.
// grid = (6, 12, 14) = 1008 blocks (~3.94/CU, one resident pass).
// ---------------------------------------------------------------------------
__global__ __launch_bounds__(256, 4) void conv_kernel(
    const float* __restrict__ ctx, const float* __restrict__ gw,
    const float* __restrict__ gb, float* __restrict__ wts)
{
    __shared__ float tile[4][WCELLS];   // 4*340*4 = 5440 B

    const int tid  = threadIdx.x;
    const int lane = tid & 63;
    const int wv   = tid >> 6;
    const int tx0  = blockIdx.x * CTSX;
    const int by   = blockIdx.y;
    const int b    = by / (NH / CTSY);
    const int ty0  = (by - b * (NH / CTSY)) * CTSY;
    const int oc0  = blockIdx.z * OCB;            // uniform -> weights s_load
    const int wrow0 = wv * WROWS;

    int   off[NSLOT];
    float msk[NSLOT];
    bool  stv[NSLOT];
#pragma unroll
    for (int s = 0; s < NSLOT; ++s) {
        int cell = lane + s * 64;
        int r = cell / HCOLS;
        int c = cell - r * HCOLS;
        int gh = ty0 + wrow0 + r - 1;
        int gc = tx0 + c - 1;
        bool ok = (gh >= 0) && (gh < NH) && (gc >= 0) && (gc < NW);
        int ghc = min(max(gh, 0), NH - 1);
        int gcc = min(max(gc, 0), NW - 1);
        off[s] = ghc * NW + gcc;
        msk[s] = ok ? 1.f : 0.f;
        stv[s] = (cell < WCELLS);
    }

    const float* cb  = ctx + (b * NC) * HW;
    float*       myt = tile[wv];

    {   // prologue: stage ic = 0
        float t[NSLOT];
#pragma unroll
        for (int s = 0; s < NSLOT; ++s) t[s] = cb[off[s]] * msk[s];
#pragma unroll
        for (int s = 0; s < NSLOT; ++s)
            if (stv[s]) myt[lane + s * 64] = t[s];
    }

    float acc[OCB][4];
#pragma unroll
    for (int oc = 0; oc < OCB; ++oc) {
        float bv = gb[oc0 + oc];
#pragma unroll
        for (int k = 0; k < 4; ++k) acc[oc][k] = bv;
    }

    const int strip = lane >> 5;        // 0/1 -> rows strip*4 .. strip*4+3
    const int col   = lane & 31;
    const float* t0 = myt + (strip * 4) * HCOLS + col;

    for (int ic = 0; ic < NC; ++ic) {
        float nxt[NSLOT];
        if (ic + 1 < NC) {
            const float* src = cb + (ic + 1) * HW;
#pragma unroll
            for (int s = 0; s < NSLOT; ++s) nxt[s] = src[off[s]] * msk[s];
        }

        float v[6][3];
#pragma unroll
        for (int j = 0; j < 6; ++j)
#pragma unroll
            for (int c = 0; c < 3; ++c)
                v[j][c] = t0[j * HCOLS + c];

        const float* wb = gw + (oc0 * NC + ic) * 9;
#pragma unroll
        for (int oc = 0; oc < OCB; ++oc) {
            const float* w9 = wb + oc * (NC * 9);
            float w00 = w9[0], w01 = w9[1], w02 = w9[2];
            float w10 = w9[3], w11 = w9[4], w12 = w9[5];
            float w20 = w9[6], w21 = w9[7], w22 = w9[8];
#pragma unroll
            for (int k = 0; k < 4; ++k) {
                acc[oc][k] += v[k][0] * w00 + v[k][1] * w01 + v[k][2] * w02
                            + v[k + 1][0] * w10 + v[k + 1][1] * w11 + v[k + 1][2] * w12
                            + v[k + 2][0] * w20 + v[k + 2][1] * w21 + v[k + 2][2] * w22;
            }
        }

        if (ic + 1 < NC) {
#pragma unroll
            for (int s = 0; s < NSLOT; ++s)
                if (stv[s]) myt[lane + s * 64] = nxt[s];
        }
    }

    const int pbase = b * HW + (ty0 + wrow0 + strip * 4) * NW + (tx0 + col);
#pragma unroll
    for (int oc = 0; oc < OCB; ++oc)
#pragma unroll
        for (int k = 0; k < 4; ++k)
            wts[(oc0 + oc) * NP + pbase + k * NW] = acc[oc][k];
}

// ---------------------------------------------------------------------------
// kan helpers
// ---------------------------------------------------------------------------
__device__ __forceinline__ float spline_part(float xv, const float* cb, int d)
{
    // cardinal cubic B-spline on uniform knots; cb = scoef + q*64 + lane,
    // coef at LDS word (d*8+jc)*128 + q*64 + lane -> bank = lane%32 (2-way,
    // free).
    float t = (xv + 2.2f) * 2.5f;
    float fi = floorf(t);
    int i = (int)fi;
    float u = t - fi;
    float u2 = u * u, u3 = u2 * u;
    float um = 1.f - u;
    float w0 = um * um * um * (1.f / 6.f);
    float w3 = u3 * (1.f / 6.f);
    float w1 = (3.f * u3 - 6.f * u2 + 4.f) * (1.f / 6.f);
    float w2 = 1.f - w0 - w1 - w3;          // partition of unity
    int j0 = i - 3;
    float sd = 0.f;
#pragma unroll
    for (int k = 0; k < 4; ++k) {
        int j = j0 + k;
        bool valid = (j >= 0) && (j <= 7);
        int jc = valid ? j : 0;
        float wk = (k == 0) ? w0 : (k == 1) ? w1 : (k == 2) ? w2 : w3;
        float cf = cb[(d * NBASIS + jc) * KPX];
        sd += (valid ? wk : 0.f) * cf;
    }
    return sd;
}

__device__ __forceinline__ float silu(float xv)
{
    return xv / (1.f + __expf(-xv));
}

// ---------------------------------------------------------------------------
// Kernel 3 (v9): block = 256 threads / 128 px; each lane owns a px PAIR ->
// all x loads are float2 (8 B/lane), out stores float2. Channels split
// 2-way across blockIdx.y (y=0: c0-15, y=1: c16-30); each wave takes 4
// channels as 2 pairs -> 4 independent spline chains per d. Wave 3 of y=1
// covers c27-30 (c27 duplicated by waves 2&3 -> identical value, benign).
// LDS scoef[k][q][64] (35.8 KB): staging writes and gathers both hit
// bank = lane%32 -> exactly 2/bank = free.
// grid = (576, 2) = 1152 blocks -> ~4.5 blocks/CU, 18 waves/CU.
// ---------------------------------------------------------------------------
__global__ __launch_bounds__(256, 4) void kan_kernel(
    const float* __restrict__ x, const float* __restrict__ wts,
    float* __restrict__ out)
{
    __shared__ float scoef[KP * KPX];   // 70*128*4 = 35840 B
    const int tid = threadIdx.x;
    const int p0  = blockIdx.x * KPX;

    // stage: thread handles (k, g): float2 of px (2g, 2g+1) -> q-split LDS
    for (int f = tid; f < KP * 64; f += 256) {
        int k = f >> 6;
        int g = f & 63;
        float2 v = *(const float2*)(wts + (size_t)k * NP + p0 + g * 2);
        scoef[k * KPX + g]      = v.x;   // q = 0
        scoef[k * KPX + 64 + g] = v.y;   // q = 1
    }
    __syncthreads();

    const int lane = tid & 63;
    const int wv   = tid >> 6;
    const int b    = p0 / HW;             // uniform (HW % 128 == 0)
    const int hw   = (p0 - b * HW) + lane * 2;

    const float* cb0 = scoef + lane;       // q = 0
    const float* cb1 = scoef + 64 + lane;  // q = 1

    // uw/rw for both pixels of the pair
    float uw0[ND], uw1[ND], rw0[ND], rw1[ND];
#pragma unroll
    for (int d = 0; d < ND; ++d) {
        uw0[d] = cb0[(CLEN + d) * KPX];
        uw1[d] = cb1[(CLEN + d) * KPX];
        rw0[d] = cb0[(CLEN + ND + d) * KPX];
        rw1[d] = cb1[(CLEN + ND + d) * KPX];
    }

    const int cy = blockIdx.y;
    const int c_begin = (cy == 0) ? wv * 4
                                  : ((wv == 3) ? 27 : 16 + wv * 4);

    const float* xb = x + (size_t)(b * NC) * (ND * HW) + hw;
    float* ob = out + (b * NC) * HW + hw;

#pragma unroll
    for (int i = 0; i < 2; ++i) {
        const int c0 = c_begin + 2 * i;
        const int c1 = c0 + 1;
        const float* x0 = xb + (size_t)c0 * ND * HW;
        const float* x1 = xb + (size_t)c1 * ND * HW;
        float s0x = 0.f, s0y = 0.f, s1x = 0.f, s1y = 0.f;
#pragma unroll
        for (int d = 0; d < ND; ++d) {
            float2 xv0 = *(const float2*)(x0 + d * HW);
            float2 xv1 = *(const float2*)(x1 + d * HW);
            s0x += uw0[d] * spline_part(xv0.x, cb0, d) + rw0[d] * silu(xv0.x);
            s0y += uw1[d] * spline_part(xv0.y, cb1, d) + rw1[d] * silu(xv0.y);
            s1x += uw0[d] * spline_part(xv1.x, cb0, d) + rw0[d] * silu(xv1.x);
            s1y += uw1[d] * spline_part(xv1.y, cb1, d) + rw1[d] * silu(xv1.y);
        }
        float2 o0; o0.x = s0x; o0.y = s0y;
        float2 o1; o1.x = s1x; o1.y = s1y;
        *(float2*)(ob + (size_t)c0 * HW) = o0;
        *(float2*)(ob + (size_t)c1 * HW) = o1;
    }
}

// ---------------------------------------------------------------------------
extern "C" void kernel_launch(void* const* d_in, const int* in_sizes, int n_in,
                              void* d_out, int out_size, void* d_ws, size_t ws_size,
                              hipStream_t stream)
{
    const float* x  = (const float*)d_in[0];   // (2,31,7,192,192)
    const float* gw = (const float*)d_in[1];   // (70,31,3,3)
    const float* gb = (const float*)d_in[2];   // (70,)
    float* out = (float*)d_out;                // (2,31,192,192)

    float* ctx = (float*)d_ws;                       // 9.1 MB
    float* wts = ctx + (size_t)NBATCH * NC * HW;     // 20.6 MB

    int n4 = NBATCH * NC * (HW / 4);
    ctx_mean_kernel<<<dim3((n4 + 255) / 256), 256, 0, stream>>>(
        (const float4*)x, (float4*)ctx);
    conv_kernel<<<dim3(NW / CTSX, (NH / CTSY) * NBATCH, KP / OCB), 256, 0, stream>>>(ctx, gw, gb, wts);
    kan_kernel<<<dim3(NP / KPX, 2), 256, 0, stream>>>(x, wts, out);
}

// Round 2
// 165.505 us; speedup vs baseline: 1.0254x; 1.0254x over previous
//
#include <hip/hip_runtime.h>
#include <math.h>

// Problem constants (GroupedKANLayer): B=2, C=31, D=7, H=W=192
#define NBATCH 2
#define NC 31
#define ND 7
#define NH 192
#define NW 192
#define HW (NH * NW)            // 36864
#define NP (NBATCH * HW)        // 73728 pixels
#define NBASIS 8
#define CLEN 56                 // ND * NBASIS
#define KP 70                   // CLEN + ND + ND
#define OCB 5                   // 70 = 14 * 5 -> 45 weight SGPRs/ic

// conv tiling (R7): 32x32 tile, wave-private 8-row strips, zero barriers,
// register-pipelined staging. Each thread: 4 pixel rows x 5 oc ->
// 180 FMA / 18 ds_reads per ic.
#define CTSX 32
#define CTSY 32
#define WROWS 8                 // tile rows per wave
#define HROWS 10                // halo rows per wave (8 + 2)
#define HCOLS 34                // halo cols
#define WCELLS (HROWS * HCOLS)  // 340 words per wave
#define NSLOT 6                 // ceil(340/64) staging slots per lane

// kan v10 tiling: 64 px per block (1 px/lane), 2-way channel split ->
// LDS 17.9 KB -> 8 blocks/CU -> 100% occupancy cap.
#define KPX 64

// ---------------------------------------------------------------------------
// Kernel 1: ctx = mean_d x, float4-vectorized (16 B/lane).
// ---------------------------------------------------------------------------
__global__ __launch_bounds__(256) void ctx_mean_kernel(
    const float4* __restrict__ x4, float4* __restrict__ ctx4)
{
    const int HW4 = HW / 4;
    int idx = blockIdx.x * 256 + threadIdx.x;      // over NBATCH*NC*HW4
    if (idx >= NBATCH * NC * HW4) return;
    int hw4 = idx % HW4;
    int bc  = idx / HW4;
    const float4* src = x4 + (size_t)bc * (ND * HW4) + hw4;
    float4 a = src[0];
#pragma unroll
    for (int d = 1; d < ND; ++d) {
        float4 v = src[d * HW4];
        a.x += v.x; a.y += v.y; a.z += v.z; a.w += v.w;
    }
    const float inv = 1.0f / 7.0f;
    a.x *= inv; a.y *= inv; a.z *= inv; a.w *= inv;
    ctx4[idx] = a;
}

// ---------------------------------------------------------------------------
// Kernel 2 (R7): 32x32 tile, 5 oc per block (blockIdx.z -> s_loads).
// Wave-private 10x34 halo strips in LDS, zero barriers, register-pipelined
// staging. grid = (6, 12, 14) = 1008 blocks.
// ---------------------------------------------------------------------------
__global__ __launch_bounds__(256, 4) void conv_kernel(
    const float* __restrict__ ctx, const float* __restrict__ gw,
    const float* __restrict__ gb, float* __restrict__ wts)
{
    __shared__ float tile[4][WCELLS];   // 4*340*4 = 5440 B

    const int tid  = threadIdx.x;
    const int lane = tid & 63;
    const int wv   = tid >> 6;
    const int tx0  = blockIdx.x * CTSX;
    const int by   = blockIdx.y;
    const int b    = by / (NH / CTSY);
    const int ty0  = (by - b * (NH / CTSY)) * CTSY;
    const int oc0  = blockIdx.z * OCB;            // uniform -> weights s_load
    const int wrow0 = wv * WROWS;

    int   off[NSLOT];
    float msk[NSLOT];
    bool  stv[NSLOT];
#pragma unroll
    for (int s = 0; s < NSLOT; ++s) {
        int cell = lane + s * 64;
        int r = cell / HCOLS;
        int c = cell - r * HCOLS;
        int gh = ty0 + wrow0 + r - 1;
        int gc = tx0 + c - 1;
        bool ok = (gh >= 0) && (gh < NH) && (gc >= 0) && (gc < NW);
        int ghc = min(max(gh, 0), NH - 1);
        int gcc = min(max(gc, 0), NW - 1);
        off[s] = ghc * NW + gcc;
        msk[s] = ok ? 1.f : 0.f;
        stv[s] = (cell < WCELLS);
    }

    const float* cb  = ctx + (b * NC) * HW;
    float*       myt = tile[wv];

    {   // prologue: stage ic = 0
        float t[NSLOT];
#pragma unroll
        for (int s = 0; s < NSLOT; ++s) t[s] = cb[off[s]] * msk[s];
#pragma unroll
        for (int s = 0; s < NSLOT; ++s)
            if (stv[s]) myt[lane + s * 64] = t[s];
    }

    float acc[OCB][4];
#pragma unroll
    for (int oc = 0; oc < OCB; ++oc) {
        float bv = gb[oc0 + oc];
#pragma unroll
        for (int k = 0; k < 4; ++k) acc[oc][k] = bv;
    }

    const int strip = lane >> 5;        // 0/1 -> rows strip*4 .. strip*4+3
    const int col   = lane & 31;
    const float* t0 = myt + (strip * 4) * HCOLS + col;

    for (int ic = 0; ic < NC; ++ic) {
        float nxt[NSLOT];
        if (ic + 1 < NC) {
            const float* src = cb + (ic + 1) * HW;
#pragma unroll
            for (int s = 0; s < NSLOT; ++s) nxt[s] = src[off[s]] * msk[s];
        }

        float v[6][3];
#pragma unroll
        for (int j = 0; j < 6; ++j)
#pragma unroll
            for (int c = 0; c < 3; ++c)
                v[j][c] = t0[j * HCOLS + c];

        const float* wb = gw + (oc0 * NC + ic) * 9;
#pragma unroll
        for (int oc = 0; oc < OCB; ++oc) {
            const float* w9 = wb + oc * (NC * 9);
            float w00 = w9[0], w01 = w9[1], w02 = w9[2];
            float w10 = w9[3], w11 = w9[4], w12 = w9[5];
            float w20 = w9[6], w21 = w9[7], w22 = w9[8];
#pragma unroll
            for (int k = 0; k < 4; ++k) {
                acc[oc][k] += v[k][0] * w00 + v[k][1] * w01 + v[k][2] * w02
                            + v[k + 1][0] * w10 + v[k + 1][1] * w11 + v[k + 1][2] * w12
                            + v[k + 2][0] * w20 + v[k + 2][1] * w21 + v[k + 2][2] * w22;
            }
        }

        if (ic + 1 < NC) {
#pragma unroll
            for (int s = 0; s < NSLOT; ++s)
                if (stv[s]) myt[lane + s * 64] = nxt[s];
        }
    }

    const int pbase = b * HW + (ty0 + wrow0 + strip * 4) * NW + (tx0 + col);
#pragma unroll
    for (int oc = 0; oc < OCB; ++oc)
#pragma unroll
        for (int k = 0; k < 4; ++k)
            wts[(oc0 + oc) * NP + pbase + k * NW] = acc[oc][k];
}

// ---------------------------------------------------------------------------
// kan helpers
// ---------------------------------------------------------------------------
__device__ __forceinline__ float spline_part(float xv, const float* cb, int d)
{
    // cardinal cubic B-spline on uniform knots; cb = scoef + lane,
    // coef at LDS word (d*8+jc)*64 + lane -> bank = lane%32 (2-way, free).
    float t = __builtin_fmaf(xv, 2.5f, 5.5f);   // (xv + 2.2) * 2.5
    float fi = floorf(t);
    int i = (int)fi;
    float u = t - fi;
    float u2 = u * u, u3 = u2 * u;
    float um = 1.f - u;
    float w0 = um * um * um * (1.f / 6.f);
    float w3 = u3 * (1.f / 6.f);
    float w1 = (3.f * u3 - 6.f * u2 + 4.f) * (1.f / 6.f);
    float w2 = 1.f - w0 - w1 - w3;          // partition of unity
    int j0 = i - 3;
    float sd = 0.f;
#pragma unroll
    for (int k = 0; k < 4; ++k) {
        int j = j0 + k;
        bool valid = ((unsigned)j) < 8u;    // single unsigned cmp
        int jc = j & 7;                     // in-range address always
        float wk = (k == 0) ? w0 : (k == 1) ? w1 : (k == 2) ? w2 : w3;
        float cf = cb[(d * NBASIS + jc) * KPX];
        sd += (valid ? wk : 0.f) * cf;
    }
    return sd;
}

__device__ __forceinline__ float silu(float xv)
{
    return xv / (1.f + __expf(-xv));
}

// ---------------------------------------------------------------------------
// Kernel 3 (v10): block = 256 threads / 64 px (1 px per lane). LDS
// scoef[k][64] = 17.9 KB -> 8 blocks/CU -> 100% occupancy cap (was 50%).
// Channels split 2-way across blockIdx.y (y=0: c0-15, y=1: c16-30); each
// wave takes 4 channels -> 4 independent spline chains per d. Wave 3 of
// y=1 covers c27-30 (c27 duplicated by waves 2&3 -> identical value,
// benign). Coefficient gathers hit bank = lane%32 -> exactly 2/bank = free.
// grid = (1152, 2) = 2304 blocks x 4 waves = 9216 waves -> fills all 8192
// wave slots in one pass (was 4608 waves vs 4-block/CU LDS cap).
// ---------------------------------------------------------------------------
__global__ __launch_bounds__(256, 8) void kan_kernel(
    const float* __restrict__ x, const float* __restrict__ wts,
    float* __restrict__ out)
{
    __shared__ float scoef[KP * KPX];   // 70*64*4 = 17920 B
    const int tid = threadIdx.x;
    const int p0  = blockIdx.x * KPX;

    // stage: 70 rows x 32 float2 = 2240 float2 loads, 256 threads
    for (int f = tid; f < KP * 32; f += 256) {
        int k = f >> 5;
        int g = f & 31;
        float2 v = *(const float2*)(wts + (size_t)k * NP + p0 + g * 2);
        *(float2*)(scoef + k * KPX + g * 2) = v;
    }
    __syncthreads();

    const int lane = tid & 63;
    const int wv   = tid >> 6;
    const int b    = p0 / HW;             // uniform (HW % 64 == 0)
    const int hw   = (p0 - b * HW) + lane;

    const float* cb = scoef + lane;

    // uw/rw for this pixel
    float uw[ND], rw[ND];
#pragma unroll
    for (int d = 0; d < ND; ++d) {
        uw[d] = cb[(CLEN + d) * KPX];
        rw[d] = cb[(CLEN + ND + d) * KPX];
    }

    const int cy = blockIdx.y;
    const int c_begin = (cy == 0) ? wv * 4
                                  : ((wv == 3) ? 27 : 16 + wv * 4);

    const float* xb = x + (size_t)(b * NC) * (ND * HW) + hw;
    float* ob = out + (b * NC) * HW + hw;

    float acc[4] = {0.f, 0.f, 0.f, 0.f};
#pragma unroll
    for (int d = 0; d < ND; ++d) {
        float xv[4];
#pragma unroll
        for (int j = 0; j < 4; ++j)
            xv[j] = xb[((size_t)(c_begin + j) * ND + d) * HW];
#pragma unroll
        for (int j = 0; j < 4; ++j)
            acc[j] += uw[d] * spline_part(xv[j], cb, d) + rw[d] * silu(xv[j]);
    }
#pragma unroll
    for (int j = 0; j < 4; ++j)
        ob[(size_t)(c_begin + j) * HW] = acc[j];
}

// ---------------------------------------------------------------------------
extern "C" void kernel_launch(void* const* d_in, const int* in_sizes, int n_in,
                              void* d_out, int out_size, void* d_ws, size_t ws_size,
                              hipStream_t stream)
{
    const float* x  = (const float*)d_in[0];   // (2,31,7,192,192)
    const float* gw = (const float*)d_in[1];   // (70,31,3,3)
    const float* gb = (const float*)d_in[2];   // (70,)
    float* out = (float*)d_out;                // (2,31,192,192)

    float* ctx = (float*)d_ws;                       // 9.1 MB
    float* wts = ctx + (size_t)NBATCH * NC * HW;     // 20.6 MB

    int n4 = NBATCH * NC * (HW / 4);
    ctx_mean_kernel<<<dim3((n4 + 255) / 256), 256, 0, stream>>>(
        (const float4*)x, (float4*)ctx);
    conv_kernel<<<dim3(NW / CTSX, (NH / CTSY) * NBATCH, KP / OCB), 256, 0, stream>>>(ctx, gw, gb, wts);
    kan_kernel<<<dim3(NP / KPX, 2), 256, 0, stream>>>(x, wts, out);
}

// Round 3
// 142.676 us; speedup vs baseline: 1.1895x; 1.1600x over previous
//
#include <hip/hip_runtime.h>
#include <math.h>

// Problem constants (GroupedKANLayer): B=2, C=31, D=7, H=W=192
#define NBATCH 2
#define NC 31
#define ND 7
#define NH 192
#define NW 192
#define HW (NH * NW)            // 36864
#define NP (NBATCH * HW)        // 73728 pixels
#define NBASIS 8
#define CLEN 56                 // ND * NBASIS
#define KP 70                   // CLEN + ND + ND

// ctx_mean grid split: first N4/256 blocks do the mean, next 90 do bf16
// weight transform.
#define N4 (NBATCH * NC * (HW / 4))     // 571392 = 2232 * 256 exactly
#define GWB_N (9 * 80 * 32)             // 23040 bf16 weights, padded

// conv-mfma LDS geometry (ushort units)
#define A_WORDS (9 * 80 * 32)           // 23040  (46080 B)
#define B_WORDS (3 * 66 * 32)           // 6336   (12672 B)

// kan v10 tiling: 64 px per block (1 px/lane), 2-way channel split ->
// LDS 17.9 KB -> 8 blocks/CU -> 100% occupancy cap.
#define KPX 64

typedef __attribute__((ext_vector_type(8))) short s16x8;
typedef __attribute__((ext_vector_type(4))) float f32x4;

__device__ __forceinline__ unsigned short f2bf(float f)
{
    unsigned u = __float_as_uint(f);
    u += 0x7FFFu + ((u >> 16) & 1u);     // round-to-nearest-even
    return (unsigned short)(u >> 16);
}

// ---------------------------------------------------------------------------
// Kernel 1: ctx = mean_d x (float4, 16 B/lane) + folded weight transform:
// gwb[s][m(80)][ic(32)] = bf16(gw[m][ic][dy][dx]), zero-padded. gwb lives at
// the head of d_out (overwritten later by kan -- stream-ordered, safe).
// ---------------------------------------------------------------------------
__global__ __launch_bounds__(256) void ctx_mean_kernel(
    const float4* __restrict__ x4, float4* __restrict__ ctx4,
    const float* __restrict__ gw, unsigned short* __restrict__ gwb)
{
    const int HW4 = HW / 4;
    int idx = blockIdx.x * 256 + threadIdx.x;
    if (idx < N4) {
        int hw4 = idx % HW4;
        int bc  = idx / HW4;
        const float4* src = x4 + (size_t)bc * (ND * HW4) + hw4;
        float4 a = src[0];
#pragma unroll
        for (int d = 1; d < ND; ++d) {
            float4 v = src[d * HW4];
            a.x += v.x; a.y += v.y; a.z += v.z; a.w += v.w;
        }
        const float inv = 1.0f / 7.0f;
        a.x *= inv; a.y *= inv; a.z *= inv; a.w *= inv;
        ctx4[idx] = a;
        return;
    }
    int e = idx - N4;
    if (e < GWB_N) {
        int s  = e / 2560;          // 80*32
        int r  = e - s * 2560;
        int m  = r >> 5;
        int ic = r & 31;
        float v = (m < KP && ic < NC) ? gw[m * (NC * 9) + ic * 9 + s] : 0.f;
        gwb[e] = f2bf(v);
    }
}

// ---------------------------------------------------------------------------
// Kernel 2 (R8, MFMA): conv as 9 accumulated GEMMs over shifted ctx.
// Block = 64-px row strip x all 70 oc (padded 80). grid = 1152 blocks.
// LDS: A = gwb copy [9][80][32] bf16 (46 KB), B = ctx tile [3][66][32] bf16
// (12.7 KB, ic-contiguous -> ds_read_b128 fragments). One barrier.
// Per wave (16 px): 9 B-frags + 45 A-frags + 45 mfma_f32_16x16x32_bf16.
// Fragment layout (m89-verified): A row=lane&15,k=(lane>>4)*8+j;
// B col=lane&15, same k; D col=lane&15, row=(lane>>4)*4+j.
// ---------------------------------------------------------------------------
__global__ __launch_bounds__(256) void conv_kernel(
    const float* __restrict__ ctx, const unsigned short* __restrict__ gwb,
    const float* __restrict__ gb, float* __restrict__ wts)
{
    __shared__ __align__(16) unsigned short AB[A_WORDS + B_WORDS]; // 58752 B

    const int tid  = threadIdx.x;
    const int lane = tid & 63;
    const int wv   = tid >> 6;
    const int gr   = blockIdx.x / 3;          // global row 0..383
    const int x0   = (blockIdx.x % 3) * 64;
    const int b    = gr / NH;
    const int y    = gr - b * NH;

    // stage A: straight 46080-B copy (layout identical global -> LDS)
    {
        const uint4* gs = (const uint4*)gwb;
        uint4*       gd = (uint4*)AB;
        for (int f = tid; f < A_WORDS / 8; f += 256) gd[f] = gs[f];
    }

    // stage B: thread = halo cell (row 0..2, col 0..65); 31 strided ctx
    // reads -> bf16 pack (ic-contiguous, ic=31 padded 0) -> 4 b128 writes.
    if (tid < 3 * 66) {
        int row = tid / 66;
        int col = tid - row * 66;
        int gy = y + row - 1, gx = x0 + col - 1;
        bool ok = (gy >= 0) && (gy < NH) && (gx >= 0) && (gx < NW);
        int cgy = ok ? gy : 0, cgx = ok ? gx : 0;
        const float* src = ctx + (size_t)(b * NC) * HW + cgy * NW + cgx;
        unsigned dw[16];
        if (ok) {
            float v[NC];
#pragma unroll
            for (int ic = 0; ic < NC; ++ic) v[ic] = src[(size_t)ic * HW];
#pragma unroll
            for (int j = 0; j < 16; ++j) {
                unsigned lo = f2bf(v[2 * j]);
                unsigned hi = (2 * j + 1 < NC) ? (unsigned)f2bf(v[2 * j + 1]) : 0u;
                dw[j] = lo | (hi << 16);
            }
        } else {
#pragma unroll
            for (int j = 0; j < 16; ++j) dw[j] = 0u;
        }
        uint4* dst = (uint4*)(AB + A_WORDS + tid * 32);
#pragma unroll
        for (int q = 0; q < 4; ++q)
            dst[q] = make_uint4(dw[4 * q], dw[4 * q + 1], dw[4 * q + 2], dw[4 * q + 3]);
    }
    __syncthreads();

    const int lm = lane & 15;
    const int kb = lane >> 4;

    f32x4 acc[5];
#pragma unroll
    for (int mt = 0; mt < 5; ++mt)
#pragma unroll
        for (int j = 0; j < 4; ++j) {
            int m = mt * 16 + kb * 4 + j;
            acc[mt][j] = (m < KP) ? gb[m] : 0.f;
        }

    const unsigned short* ap = AB + lm * 32 + kb * 8;
    const unsigned short* bp = AB + A_WORDS + (wv * 16 + lm) * 32 + kb * 8;

#pragma unroll
    for (int s = 0; s < 9; ++s) {
        const int dy = s / 3, dx = s % 3;
        s16x8 bf = *(const s16x8*)(bp + (dy * 66 + dx) * 32);
#pragma unroll
        for (int mt = 0; mt < 5; ++mt) {
            s16x8 af = *(const s16x8*)(ap + (s * 80 + mt * 16) * 32);
            acc[mt] = __builtin_amdgcn_mfma_f32_16x16x32_bf16(af, bf, acc[mt], 0, 0, 0);
        }
    }

    const int p = blockIdx.x * 64 + wv * 16 + lm;
#pragma unroll
    for (int mt = 0; mt < 5; ++mt)
#pragma unroll
        for (int j = 0; j < 4; ++j) {
            int m = mt * 16 + kb * 4 + j;
            if (m < KP) wts[(size_t)m * NP + p] = acc[mt][j];
        }
}

// ---------------------------------------------------------------------------
// kan helpers
// ---------------------------------------------------------------------------
__device__ __forceinline__ float spline_part(float xv, const float* cb, int d)
{
    // cardinal cubic B-spline on uniform knots; cb = scoef + lane,
    // coef at LDS word (d*8+jc)*64 + lane -> bank = lane%32 (2-way, free).
    float t = __builtin_fmaf(xv, 2.5f, 5.5f);   // (xv + 2.2) * 2.5
    float fi = floorf(t);
    int i = (int)fi;
    float u = t - fi;
    float u2 = u * u, u3 = u2 * u;
    float um = 1.f - u;
    float w0 = um * um * um * (1.f / 6.f);
    float w3 = u3 * (1.f / 6.f);
    float w1 = (3.f * u3 - 6.f * u2 + 4.f) * (1.f / 6.f);
    float w2 = 1.f - w0 - w1 - w3;          // partition of unity
    int j0 = i - 3;
    float sd = 0.f;
#pragma unroll
    for (int k = 0; k < 4; ++k) {
        int j = j0 + k;
        bool valid = ((unsigned)j) < 8u;    // single unsigned cmp
        int jc = j & 7;                     // in-range address always
        float wk = (k == 0) ? w0 : (k == 1) ? w1 : (k == 2) ? w2 : w3;
        float cf = cb[(d * NBASIS + jc) * KPX];
        sd += (valid ? wk : 0.f) * cf;
    }
    return sd;
}

__device__ __forceinline__ float silu(float xv)
{
    return xv / (1.f + __expf(-xv));
}

// ---------------------------------------------------------------------------
// Kernel 3 (v10): block = 256 threads / 64 px (1 px per lane). LDS
// scoef[k][64] = 17.9 KB -> 8 blocks/CU -> 100% occupancy cap.
// Channels split 2-way across blockIdx.y; each wave takes 4 channels.
// Wave 3 of y=1 covers c27-30 (c27 duplicated by waves 2&3 -> benign).
// grid = (1152, 2) = 2304 blocks x 4 waves = 9216 waves.
// ---------------------------------------------------------------------------
__global__ __launch_bounds__(256, 8) void kan_kernel(
    const float* __restrict__ x, const float* __restrict__ wts,
    float* __restrict__ out)
{
    __shared__ float scoef[KP * KPX];   // 70*64*4 = 17920 B
    const int tid = threadIdx.x;
    const int p0  = blockIdx.x * KPX;

    // stage: 70 rows x 32 float2 = 2240 float2 loads, 256 threads
    for (int f = tid; f < KP * 32; f += 256) {
        int k = f >> 5;
        int g = f & 31;
        float2 v = *(const float2*)(wts + (size_t)k * NP + p0 + g * 2);
        *(float2*)(scoef + k * KPX + g * 2) = v;
    }
    __syncthreads();

    const int lane = tid & 63;
    const int wv   = tid >> 6;
    const int b    = p0 / HW;             // uniform (HW % 64 == 0)
    const int hw   = (p0 - b * HW) + lane;

    const float* cb = scoef + lane;

    // uw/rw for this pixel
    float uw[ND], rw[ND];
#pragma unroll
    for (int d = 0; d < ND; ++d) {
        uw[d] = cb[(CLEN + d) * KPX];
        rw[d] = cb[(CLEN + ND + d) * KPX];
    }

    const int cy = blockIdx.y;
    const int c_begin = (cy == 0) ? wv * 4
                                  : ((wv == 3) ? 27 : 16 + wv * 4);

    const float* xb = x + (size_t)(b * NC) * (ND * HW) + hw;
    float* ob = out + (b * NC) * HW + hw;

    float acc[4] = {0.f, 0.f, 0.f, 0.f};
#pragma unroll
    for (int d = 0; d < ND; ++d) {
        float xv[4];
#pragma unroll
        for (int j = 0; j < 4; ++j)
            xv[j] = xb[((size_t)(c_begin + j) * ND + d) * HW];
#pragma unroll
        for (int j = 0; j < 4; ++j)
            acc[j] += uw[d] * spline_part(xv[j], cb, d) + rw[d] * silu(xv[j]);
    }
#pragma unroll
    for (int j = 0; j < 4; ++j)
        ob[(size_t)(c_begin + j) * HW] = acc[j];
}

// ---------------------------------------------------------------------------
extern "C" void kernel_launch(void* const* d_in, const int* in_sizes, int n_in,
                              void* d_out, int out_size, void* d_ws, size_t ws_size,
                              hipStream_t stream)
{
    const float* x  = (const float*)d_in[0];   // (2,31,7,192,192)
    const float* gw = (const float*)d_in[1];   // (70,31,3,3)
    const float* gb = (const float*)d_in[2];   // (70,)
    float* out = (float*)d_out;                // (2,31,192,192)

    float* ctx = (float*)d_ws;                       // 9.1 MB
    float* wts = ctx + (size_t)NBATCH * NC * HW;     // 20.6 MB
    // 46 KB bf16 weight buffer parked at the head of d_out: written by
    // ctx_mean, read by conv, then fully overwritten by kan. Stream-ordered.
    unsigned short* gwb = (unsigned short*)d_out;

    ctx_mean_kernel<<<dim3(N4 / 256 + (GWB_N + 255) / 256), 256, 0, stream>>>(
        (const float4*)x, (float4*)ctx, gw, gwb);
    conv_kernel<<<dim3(NP / 64), 256, 0, stream>>>(ctx, gwb, gb, wts);
    kan_kernel<<<dim3(NP / KPX, 2), 256, 0, stream>>>(x, wts, out);
}

// Round 4
// 139.554 us; speedup vs baseline: 1.2161x; 1.0224x over previous
//
#include <hip/hip_runtime.h>
#include <math.h>

// Problem constants (GroupedKANLayer): B=2, C=31, D=7, H=W=192
#define NBATCH 2
#define NC 31
#define ND 7
#define NH 192
#define NW 192
#define HW (NH * NW)            // 36864
#define NP (NBATCH * HW)        // 73728 pixels
#define NBASIS 8
#define CLEN 56                 // ND * NBASIS
#define KP 70                   // CLEN + ND + ND

// ctx_mean grid split: first N4/256 blocks do the mean, next 90 do bf16
// weight transform.
#define N4 (NBATCH * NC * (HW / 4))     // 571392 = 2232 * 256 exactly
#define GWB_N (9 * 80 * 32)             // 23040 bf16 weights, padded

// fused-kernel LDS geometry (ushort units)
#define A_WORDS (9 * 80 * 32)           // 23040  (46080 B)
#define B_WORDS (3 * 66 * 32)           // 6336   (12672 B)
#define SMEM_BYTES ((A_WORDS + B_WORDS) * 2)   // 58752 B -> 2 blocks/CU

#define KPX 64                  // scoef px stride (f32 words)

typedef __attribute__((ext_vector_type(8))) short s16x8;
typedef __attribute__((ext_vector_type(4))) float f32x4;

__device__ __forceinline__ unsigned short f2bf(float f)
{
    unsigned u = __float_as_uint(f);
    u += 0x7FFFu + ((u >> 16) & 1u);     // round-to-nearest-even
    return (unsigned short)(u >> 16);
}

// ---------------------------------------------------------------------------
// Kernel 1: ctx = mean_d x (float4, 16 B/lane) + folded weight transform:
// gwb[s][m(80)][ic(32)] = bf16(gw[m][ic][dy][dx]), zero-padded. gwb lives in
// the workspace right after ctx (it is read by every fused block, so it must
// NOT alias d_out, which the fused kernel writes).
// ---------------------------------------------------------------------------
__global__ __launch_bounds__(256) void ctx_mean_kernel(
    const float4* __restrict__ x4, float4* __restrict__ ctx4,
    const float* __restrict__ gw, unsigned short* __restrict__ gwb)
{
    const int HW4 = HW / 4;
    int idx = blockIdx.x * 256 + threadIdx.x;
    if (idx < N4) {
        int hw4 = idx % HW4;
        int bc  = idx / HW4;
        const float4* src = x4 + (size_t)bc * (ND * HW4) + hw4;
        float4 a = src[0];
#pragma unroll
        for (int d = 1; d < ND; ++d) {
            float4 v = src[d * HW4];
            a.x += v.x; a.y += v.y; a.z += v.z; a.w += v.w;
        }
        const float inv = 1.0f / 7.0f;
        a.x *= inv; a.y *= inv; a.z *= inv; a.w *= inv;
        ctx4[idx] = a;
        return;
    }
    int e = idx - N4;
    if (e < GWB_N) {
        int s  = e / 2560;          // 80*32
        int r  = e - s * 2560;
        int m  = r >> 5;
        int ic = r & 31;
        float v = (m < KP && ic < NC) ? gw[m * (NC * 9) + ic * 9 + s] : 0.f;
        gwb[e] = f2bf(v);
    }
}

// ---------------------------------------------------------------------------
// kan helpers
// ---------------------------------------------------------------------------
__device__ __forceinline__ float spline_part(float xv, const float* cb, int d)
{
    // cardinal cubic B-spline on uniform knots; cb = scoef + lane,
    // coef at LDS word (d*8+jc)*64 + lane -> bank = lane%32 (2-way, free).
    float t = __builtin_fmaf(xv, 2.5f, 5.5f);   // (xv + 2.2) * 2.5
    float fi = floorf(t);
    int i = (int)fi;
    float u = t - fi;
    float u2 = u * u, u3 = u2 * u;
    float um = 1.f - u;
    float w0 = um * um * um * (1.f / 6.f);
    float w3 = u3 * (1.f / 6.f);
    float w1 = (3.f * u3 - 6.f * u2 + 4.f) * (1.f / 6.f);
    float w2 = 1.f - w0 - w1 - w3;          // partition of unity
    int j0 = i - 3;
    float sd = 0.f;
#pragma unroll
    for (int k = 0; k < 4; ++k) {
        int j = j0 + k;
        bool valid = ((unsigned)j) < 8u;    // single unsigned cmp
        int jc = j & 7;                     // in-range address always
        float wk = (k == 0) ? w0 : (k == 1) ? w1 : (k == 2) ? w2 : w3;
        float cf = cb[(d * NBASIS + jc) * KPX];
        sd += (valid ? wk : 0.f) * cf;
    }
    return sd;
}

__device__ __forceinline__ float silu(float xv)
{
    return xv / (1.f + __expf(-xv));
}

// ---------------------------------------------------------------------------
// Kernel 2 (R9, FUSED conv+kan): block = 64-px row strip.
// Phase 1 (conv): 9 accumulated GEMMs M=80,K=32 over shifted ctx, bf16 MFMA.
//   LDS A = gwb copy [9][80][32] bf16 (46 KB), B = ctx halo [3][66][32] bf16
//   (12.7 KB). Per wave: 9 B-frags + 45 A-frags + 45 mfma_f32_16x16x32_bf16.
// Phase 2: D-fragments scattered to scoef[m][px] (f32, overlays dead A
//   region), one barrier each side. No global wts round-trip at all.
// Phase 3 (kan): 4 waves x 8 channels (c30 dup on wave 3, benign); per
//   thread 4 channel-pairs, 14-deep software-pipelined x loads -> spline.
// grid = 1152 blocks; LDS 58752 B -> 2 blocks/CU; latency hidden by ILP.
// ---------------------------------------------------------------------------
__global__ __launch_bounds__(256) void fused_kernel(
    const float* __restrict__ ctx, const unsigned short* __restrict__ gwb,
    const float* __restrict__ gb, const float* __restrict__ x,
    float* __restrict__ out)
{
    __shared__ __align__(16) unsigned char smem[SMEM_BYTES];
    unsigned short* A = (unsigned short*)smem;
    unsigned short* Bt = A + A_WORDS;
    float* scoef = (float*)smem;           // overlays A after phase 1

    const int tid  = threadIdx.x;
    const int lane = tid & 63;
    const int wv   = tid >> 6;
    const int gr   = blockIdx.x / 3;          // global row 0..383
    const int x0   = (blockIdx.x % 3) * 64;
    const int b    = gr / NH;
    const int y    = gr - b * NH;

    // stage A: straight 46080-B copy (layout identical global -> LDS)
    {
        const uint4* gs = (const uint4*)gwb;
        uint4*       gd = (uint4*)A;
        for (int f = tid; f < A_WORDS / 8; f += 256) gd[f] = gs[f];
    }

    // stage B: thread = halo cell (row 0..2, col 0..65); 31 strided ctx
    // reads -> bf16 pack (ic-contiguous, ic=31 padded 0) -> 4 b128 writes.
    if (tid < 3 * 66) {
        int row = tid / 66;
        int col = tid - row * 66;
        int gy = y + row - 1, gx = x0 + col - 1;
        bool ok = (gy >= 0) && (gy < NH) && (gx >= 0) && (gx < NW);
        int cgy = ok ? gy : 0, cgx = ok ? gx : 0;
        const float* src = ctx + (size_t)(b * NC) * HW + cgy * NW + cgx;
        unsigned dw[16];
        if (ok) {
            float v[NC];
#pragma unroll
            for (int ic = 0; ic < NC; ++ic) v[ic] = src[(size_t)ic * HW];
#pragma unroll
            for (int j = 0; j < 16; ++j) {
                unsigned lo = f2bf(v[2 * j]);
                unsigned hi = (2 * j + 1 < NC) ? (unsigned)f2bf(v[2 * j + 1]) : 0u;
                dw[j] = lo | (hi << 16);
            }
        } else {
#pragma unroll
            for (int j = 0; j < 16; ++j) dw[j] = 0u;
        }
        uint4* dst = (uint4*)(Bt + tid * 32);
#pragma unroll
        for (int q = 0; q < 4; ++q)
            dst[q] = make_uint4(dw[4 * q], dw[4 * q + 1], dw[4 * q + 2], dw[4 * q + 3]);
    }
    __syncthreads();

    // phase 1: MFMA. A row=lane&15, k=(lane>>4)*8+j; B col=lane&15, same k;
    // D col=lane&15, row=(lane>>4)*4+j  (m89-verified layouts).
    const int lm = lane & 15;
    const int kb = lane >> 4;

    f32x4 acc[5];
#pragma unroll
    for (int mt = 0; mt < 5; ++mt)
#pragma unroll
        for (int j = 0; j < 4; ++j) {
            int m = mt * 16 + kb * 4 + j;
            acc[mt][j] = (m < KP) ? gb[m] : 0.f;
        }

    const unsigned short* ap = A + lm * 32 + kb * 8;
    const unsigned short* bp = Bt + (wv * 16 + lm) * 32 + kb * 8;

#pragma unroll
    for (int s = 0; s < 9; ++s) {
        const int dy = s / 3, dx = s % 3;
        s16x8 bf = *(const s16x8*)(bp + (dy * 66 + dx) * 32);
#pragma unroll
        for (int mt = 0; mt < 5; ++mt) {
            s16x8 af = *(const s16x8*)(ap + (s * 80 + mt * 16) * 32);
            acc[mt] = __builtin_amdgcn_mfma_f32_16x16x32_bf16(af, bf, acc[mt], 0, 0, 0);
        }
    }
    __syncthreads();            // A, B dead

    // phase 2: D-fragments -> scoef[m][px], px = wv*16 + lm
    {
        const int px = wv * 16 + lm;
#pragma unroll
        for (int mt = 0; mt < 5; ++mt)
#pragma unroll
            for (int j = 0; j < 4; ++j) {
                int m = mt * 16 + kb * 4 + j;
                if (m < KP) scoef[m * KPX + px] = acc[mt][j];
            }
    }
    __syncthreads();

    // phase 3: kan. lane = px; wave wv covers channels wv*8 .. wv*8+7
    // (clamped to 30; wave 3 computes c30 twice -> same value, benign).
    const int hw = y * NW + x0 + lane;
    const float* cbl = scoef + lane;

    float uw[ND], rw[ND];
#pragma unroll
    for (int d = 0; d < ND; ++d) {
        uw[d] = cbl[(CLEN + d) * KPX];
        rw[d] = cbl[(CLEN + ND + d) * KPX];
    }

    const float* xb = x + (size_t)(b * NC) * (ND * HW) + hw;
    float* ob = out + (b * NC) * HW + hw;
    const int c0 = wv * 8;

    float cur[2][ND], nxt[2][ND];
    {
        int ca = min(c0, 30), cb2 = min(c0 + 1, 30);
#pragma unroll
        for (int d = 0; d < ND; ++d) {
            cur[0][d] = xb[((size_t)ca * ND + d) * HW];
            cur[1][d] = xb[((size_t)cb2 * ND + d) * HW];
        }
    }

#pragma unroll
    for (int pr = 0; pr < 4; ++pr) {
        int ca = min(c0 + 2 * pr, 30), cb2 = min(c0 + 2 * pr + 1, 30);
        if (pr < 3) {
            int na = min(c0 + 2 * pr + 2, 30), nb = min(c0 + 2 * pr + 3, 30);
#pragma unroll
            for (int d = 0; d < ND; ++d) {
                nxt[0][d] = xb[((size_t)na * ND + d) * HW];
                nxt[1][d] = xb[((size_t)nb * ND + d) * HW];
            }
        }
        float sa = 0.f, sb = 0.f;
#pragma unroll
        for (int d = 0; d < ND; ++d) {
            sa += uw[d] * spline_part(cur[0][d], cbl, d) + rw[d] * silu(cur[0][d]);
            sb += uw[d] * spline_part(cur[1][d], cbl, d) + rw[d] * silu(cur[1][d]);
        }
        ob[(size_t)ca * HW] = sa;
        ob[(size_t)cb2 * HW] = sb;
        if (pr < 3) {
#pragma unroll
            for (int d = 0; d < ND; ++d) {
                cur[0][d] = nxt[0][d];
                cur[1][d] = nxt[1][d];
            }
        }
    }
}

// ---------------------------------------------------------------------------
extern "C" void kernel_launch(void* const* d_in, const int* in_sizes, int n_in,
                              void* d_out, int out_size, void* d_ws, size_t ws_size,
                              hipStream_t stream)
{
    const float* x  = (const float*)d_in[0];   // (2,31,7,192,192)
    const float* gw = (const float*)d_in[1];   // (70,31,3,3)
    const float* gb = (const float*)d_in[2];   // (70,)
    float* out = (float*)d_out;                // (2,31,192,192)

    float* ctx = (float*)d_ws;                             // 9.1 MB
    unsigned short* gwb = (unsigned short*)(ctx + (size_t)NBATCH * NC * HW);

    ctx_mean_kernel<<<dim3(N4 / 256 + (GWB_N + 255) / 256), 256, 0, stream>>>(
        (const float4*)x, (float4*)ctx, gw, gwb);
    fused_kernel<<<dim3(NP / 64), 256, 0, stream>>>(ctx, gwb, gb, x, out);
}

// Round 5
// 135.173 us; speedup vs baseline: 1.2555x; 1.0324x over previous
//
#include <hip/hip_runtime.h>
#include <math.h>

// Problem constants (GroupedKANLayer): B=2, C=31, D=7, H=W=192
#define NBATCH 2
#define NC 31
#define ND 7
#define NH 192
#define NW 192
#define HW (NH * NW)            // 36864
#define NP (NBATCH * HW)        // 73728 pixels
#define NBASIS 8
#define CLEN 56                 // ND * NBASIS
#define KP 70                   // CLEN + ND + ND

// ctx_mean grid split: first N4/256 blocks do the mean, next 90 do bf16
// weight transform.
#define N4 (NBATCH * NC * (HW / 4))     // 571392 = 2232 * 256 exactly
#define GWB_N (9 * 80 * 32)             // 23040 bf16 weights, padded

// fused-kernel LDS geometry: B-halo (12672 B, phase 1) and scoef
// (70*64*4 = 17920 B, phases 2-3) have disjoint lifetimes -> overlaid.
// LDS = 17920 B -> occupancy is VGPR-capped at 4 blocks/CU (16 waves/CU),
// double the R9 LDS-capped 2 blocks/CU.
#define B_WORDS (3 * 66 * 32)           // 6336 ushorts (12672 B)
#define SMEM_BYTES (KP * 64 * 4)        // 17920 B

#define KPX 64                  // scoef px stride (f32 words)

typedef __attribute__((ext_vector_type(8))) short s16x8;
typedef __attribute__((ext_vector_type(4))) float f32x4;

__device__ __forceinline__ unsigned short f2bf(float f)
{
    unsigned u = __float_as_uint(f);
    u += 0x7FFFu + ((u >> 16) & 1u);     // round-to-nearest-even
    return (unsigned short)(u >> 16);
}

// ---------------------------------------------------------------------------
// Kernel 1: ctx = mean_d x (float4, 16 B/lane) + folded weight transform:
// gwb[s][m(80)][ic(32)] = bf16(gw[m][ic][dy][dx]), zero-padded. gwb lives in
// the workspace right after ctx.
// ---------------------------------------------------------------------------
__global__ __launch_bounds__(256) void ctx_mean_kernel(
    const float4* __restrict__ x4, float4* __restrict__ ctx4,
    const float* __restrict__ gw, unsigned short* __restrict__ gwb)
{
    const int HW4 = HW / 4;
    int idx = blockIdx.x * 256 + threadIdx.x;
    if (idx < N4) {
        int hw4 = idx % HW4;
        int bc  = idx / HW4;
        const float4* src = x4 + (size_t)bc * (ND * HW4) + hw4;
        float4 a = src[0];
#pragma unroll
        for (int d = 1; d < ND; ++d) {
            float4 v = src[d * HW4];
            a.x += v.x; a.y += v.y; a.z += v.z; a.w += v.w;
        }
        const float inv = 1.0f / 7.0f;
        a.x *= inv; a.y *= inv; a.z *= inv; a.w *= inv;
        ctx4[idx] = a;
        return;
    }
    int e = idx - N4;
    if (e < GWB_N) {
        int s  = e / 2560;          // 80*32
        int r  = e - s * 2560;
        int m  = r >> 5;
        int ic = r & 31;
        float v = (m < KP && ic < NC) ? gw[m * (NC * 9) + ic * 9 + s] : 0.f;
        gwb[e] = f2bf(v);
    }
}

// ---------------------------------------------------------------------------
// kan helpers
// ---------------------------------------------------------------------------
__device__ __forceinline__ float spline_part(float xv, const float* cb, int d)
{
    // cardinal cubic B-spline on uniform knots; cb = scoef + lane,
    // coef at LDS word (d*8+jc)*64 + lane -> bank = lane%32 (2-way, free).
    float t = __builtin_fmaf(xv, 2.5f, 5.5f);   // (xv + 2.2) * 2.5
    float fi = floorf(t);
    int i = (int)fi;
    float u = t - fi;
    float u2 = u * u, u3 = u2 * u;
    float um = 1.f - u;
    float w0 = um * um * um * (1.f / 6.f);
    float w3 = u3 * (1.f / 6.f);
    float w1 = (3.f * u3 - 6.f * u2 + 4.f) * (1.f / 6.f);
    float w2 = 1.f - w0 - w1 - w3;          // partition of unity
    int j0 = i - 3;
    float sd = 0.f;
#pragma unroll
    for (int k = 0; k < 4; ++k) {
        int j = j0 + k;
        bool valid = ((unsigned)j) < 8u;    // single unsigned cmp
        int jc = j & 7;                     // in-range address always
        float wk = (k == 0) ? w0 : (k == 1) ? w1 : (k == 2) ? w2 : w3;
        float cf = cb[(d * NBASIS + jc) * KPX];
        sd += (valid ? wk : 0.f) * cf;
    }
    return sd;
}

__device__ __forceinline__ float silu(float xv)
{
    return xv / (1.f + __expf(-xv));
}

// ---------------------------------------------------------------------------
// Kernel 2 (R10, FUSED conv+kan, slim LDS): block = 64-px row strip.
// Phase 1 (conv): 9 accumulated GEMMs M=80,K=32, bf16 MFMA. A-fragments are
//   loaded straight from global gwb (46 KB, L2-resident chip-wide,
//   coalesced dwordx4) -- NOT staged in LDS. Only the ctx halo B-tile
//   [3][66][32] bf16 (12.7 KB) is staged.
// Phase 2: D-fragments scattered to scoef[m][px] (17.9 KB, overlays the
//   dead B region). No global wts round-trip.
// Phase 3 (kan): 4 waves x 8 channels; first channel-pair x loads hoisted
//   above the phase-1 barrier so HBM latency hides under the MFMAs.
// LDS 17.9 KB; __launch_bounds__(256,4) -> 4 blocks/CU = 16 waves/CU
// (2x R9's LDS-capped 8 waves/CU).
// ---------------------------------------------------------------------------
__global__ __launch_bounds__(256, 4) void fused_kernel(
    const float* __restrict__ ctx, const unsigned short* __restrict__ gwb,
    const float* __restrict__ gb, const float* __restrict__ x,
    float* __restrict__ out)
{
    __shared__ __align__(16) unsigned char smem[SMEM_BYTES];
    unsigned short* Bt = (unsigned short*)smem;    // phase 1
    float* scoef = (float*)smem;                   // phases 2-3 (overlay)

    const int tid  = threadIdx.x;
    const int lane = tid & 63;
    const int wv   = tid >> 6;
    const int gr   = blockIdx.x / 3;          // global row 0..383
    const int x0   = (blockIdx.x % 3) * 64;
    const int b    = gr / NH;
    const int y    = gr - b * NH;

    // stage B: thread = halo cell (row 0..2, col 0..65); 31 strided ctx
    // reads -> bf16 pack (ic-contiguous, ic=31 padded 0) -> 4 b128 writes.
    if (tid < 3 * 66) {
        int row = tid / 66;
        int col = tid - row * 66;
        int gy = y + row - 1, gx = x0 + col - 1;
        bool ok = (gy >= 0) && (gy < NH) && (gx >= 0) && (gx < NW);
        int cgy = ok ? gy : 0, cgx = ok ? gx : 0;
        const float* src = ctx + (size_t)(b * NC) * HW + cgy * NW + cgx;
        unsigned dw[16];
        if (ok) {
            float v[NC];
#pragma unroll
            for (int ic = 0; ic < NC; ++ic) v[ic] = src[(size_t)ic * HW];
#pragma unroll
            for (int j = 0; j < 16; ++j) {
                unsigned lo = f2bf(v[2 * j]);
                unsigned hi = (2 * j + 1 < NC) ? (unsigned)f2bf(v[2 * j + 1]) : 0u;
                dw[j] = lo | (hi << 16);
            }
        } else {
#pragma unroll
            for (int j = 0; j < 16; ++j) dw[j] = 0u;
        }
        uint4* dst = (uint4*)(Bt + tid * 32);
#pragma unroll
        for (int q = 0; q < 4; ++q)
            dst[q] = make_uint4(dw[4 * q], dw[4 * q + 1], dw[4 * q + 2], dw[4 * q + 3]);
    }

    // hoist phase-3 first channel-pair x loads: latency hides under conv
    const int hw = y * NW + x0 + lane;
    const float* xb = x + (size_t)(b * NC) * (ND * HW) + hw;
    const int c0 = wv * 8;
    float cur[2][ND];
    {
        int ca = min(c0, 30), cb2 = min(c0 + 1, 30);
#pragma unroll
        for (int d = 0; d < ND; ++d) {
            cur[0][d] = xb[((size_t)ca * ND + d) * HW];
            cur[1][d] = xb[((size_t)cb2 * ND + d) * HW];
        }
    }
    __syncthreads();

    // phase 1: MFMA. A row=lane&15, k=(lane>>4)*8+j; B col=lane&15, same k;
    // D col=lane&15, row=(lane>>4)*4+j  (m89-verified layouts).
    const int lm = lane & 15;
    const int kb = lane >> 4;

    f32x4 acc[5];
#pragma unroll
    for (int mt = 0; mt < 5; ++mt)
#pragma unroll
        for (int j = 0; j < 4; ++j) {
            int m = mt * 16 + kb * 4 + j;
            acc[mt][j] = (m < KP) ? gb[m] : 0.f;
        }

    const unsigned short* ap = gwb + lm * 32 + kb * 8;      // GLOBAL (L2)
    const unsigned short* bp = Bt + (wv * 16 + lm) * 32 + kb * 8;

#pragma unroll
    for (int s = 0; s < 9; ++s) {
        const int dy = s / 3, dx = s % 3;
        s16x8 bf = *(const s16x8*)(bp + (dy * 66 + dx) * 32);
#pragma unroll
        for (int mt = 0; mt < 5; ++mt) {
            s16x8 af = *(const s16x8*)(ap + (s * 80 + mt * 16) * 32);
            acc[mt] = __builtin_amdgcn_mfma_f32_16x16x32_bf16(af, bf, acc[mt], 0, 0, 0);
        }
    }
    __syncthreads();            // B dead

    // phase 2: D-fragments -> scoef[m][px], px = wv*16 + lm
    {
        const int px = wv * 16 + lm;
#pragma unroll
        for (int mt = 0; mt < 5; ++mt)
#pragma unroll
            for (int j = 0; j < 4; ++j) {
                int m = mt * 16 + kb * 4 + j;
                if (m < KP) scoef[m * KPX + px] = acc[mt][j];
            }
    }
    __syncthreads();

    // phase 3: kan. lane = px; wave wv covers channels wv*8 .. wv*8+7
    // (clamped to 30; wave 3 computes c30 twice -> same value, benign).
    const float* cbl = scoef + lane;

    float uw[ND], rw[ND];
#pragma unroll
    for (int d = 0; d < ND; ++d) {
        uw[d] = cbl[(CLEN + d) * KPX];
        rw[d] = cbl[(CLEN + ND + d) * KPX];
    }

    float* ob = out + (b * NC) * HW + hw;

    float nxt[2][ND];
#pragma unroll
    for (int pr = 0; pr < 4; ++pr) {
        int ca = min(c0 + 2 * pr, 30), cb2 = min(c0 + 2 * pr + 1, 30);
        if (pr < 3) {
            int na = min(c0 + 2 * pr + 2, 30), nb = min(c0 + 2 * pr + 3, 30);
#pragma unroll
            for (int d = 0; d < ND; ++d) {
                nxt[0][d] = xb[((size_t)na * ND + d) * HW];
                nxt[1][d] = xb[((size_t)nb * ND + d) * HW];
            }
        }
        float sa = 0.f, sb = 0.f;
#pragma unroll
        for (int d = 0; d < ND; ++d) {
            sa += uw[d] * spline_part(cur[0][d], cbl, d) + rw[d] * silu(cur[0][d]);
            sb += uw[d] * spline_part(cur[1][d], cbl, d) + rw[d] * silu(cur[1][d]);
        }
        ob[(size_t)ca * HW] = sa;
        ob[(size_t)cb2 * HW] = sb;
        if (pr < 3) {
#pragma unroll
            for (int d = 0; d < ND; ++d) {
                cur[0][d] = nxt[0][d];
                cur[1][d] = nxt[1][d];
            }
        }
    }
}

// ---------------------------------------------------------------------------
extern "C" void kernel_launch(void* const* d_in, const int* in_sizes, int n_in,
                              void* d_out, int out_size, void* d_ws, size_t ws_size,
                              hipStream_t stream)
{
    const float* x  = (const float*)d_in[0];   // (2,31,7,192,192)
    const float* gw = (const float*)d_in[1];   // (70,31,3,3)
    const float* gb = (const float*)d_in[2];   // (70,)
    float* out = (float*)d_out;                // (2,31,192,192)

    float* ctx = (float*)d_ws;                             // 9.1 MB
    unsigned short* gwb = (unsigned short*)(ctx + (size_t)NBATCH * NC * HW);

    ctx_mean_kernel<<<dim3(N4 / 256 + (GWB_N + 255) / 256), 256, 0, stream>>>(
        (const float4*)x, (float4*)ctx, gw, gwb);
    fused_kernel<<<dim3(NP / 64), 256, 0, stream>>>(ctx, gwb, gb, x, out);
}